// Round 14
// baseline (446.440 us; speedup 1.0000x reference)
//
#include <hip/hip_runtime.h>
#include <hip/hip_bf16.h>

// ---------------------------------------------------------------------------
// PatchGAT on MI355X. Round 14: XCD-sliced aggregation — block=(slice,8-node
// chunk), slice=blockIdx&7 -> one XCD sees only a 2.56MB feat column slice
// (fits private L2); wcsr stored head-major. Pool is standalone again.
// N=20000, E=320000, F_IN=HID=OUT=128, H=4, H*D=512.
// ---------------------------------------------------------------------------

typedef __attribute__((ext_vector_type(8))) short bf16x8;
typedef __attribute__((ext_vector_type(4))) float f32x4;
typedef __hip_bfloat16 bf16_t;

#define NEG_SLOPE 0.2f

__device__ __forceinline__ unsigned int pack_bf16(float lo, float hi) {
  return (((unsigned int)__bfloat16_as_ushort(__float2bfloat16(hi))) << 16) |
         (unsigned int)__bfloat16_as_ushort(__float2bfloat16(lo));
}

__device__ __forceinline__ float leaky_exp(float e) {
  e = (e > 0.f) ? e : NEG_SLOPE * e;
  return __expf(e);
}

// async 16B global->LDS DMA; LDS dest = wave-uniform base + lane*16
__device__ __forceinline__ void gload_lds16(const void* g, void* l) {
  __builtin_amdgcn_global_load_lds(
      (const __attribute__((address_space(1))) void*)g,
      (__attribute__((address_space(3))) void*)l, 16, 0, 0);
}

// ---------------- mega-prep: ONE launch does
//  blocks [0,384):    6x [128,512]->[512,128] transposes (W,rW per layer)
//  blocks [384,512):  2x [512,128]->[128,512] transposes (DW0,DW1)
//  blocks [512,524):  ALR[L][k][c]
//  blocks [524,3024): n_feat fp32 -> bf16
//  block  3024:       zero counts[N] and d_out[128]
__global__ __launch_bounds__(256) void mega_prep(
    const float* __restrict__ W0, const float* __restrict__ rW0,
    const float* __restrict__ W1, const float* __restrict__ rW1,
    const float* __restrict__ W2, const float* __restrict__ rW2,
    const float* __restrict__ DW0, const float* __restrict__ DW1,
    const float* __restrict__ al0, const float* __restrict__ ar0,
    const float* __restrict__ al1, const float* __restrict__ ar1,
    const float* __restrict__ al2, const float* __restrict__ ar2,
    const float* __restrict__ n_feat, bf16_t* __restrict__ wts,
    float* __restrict__ ALR, bf16_t* __restrict__ xbf,
    int* __restrict__ counts, float* __restrict__ d_out_f, int N) {
  __shared__ float tile[32][33];
  int b = blockIdx.x, tid = threadIdx.x;
  int r = tid >> 5, c = tid & 31;

  if (b < 384) {  // W/rW transposes: [128,512] -> [512,128]; 6 mats x 64 tiles
    int mat = b >> 6;            // 0..5: L*2 + isR
    int t = b & 63;
    int kt = t >> 4, nt = t & 15;
    int L = mat >> 1, isR = mat & 1;
    const float* S = (L == 0) ? (isR ? rW0 : W0)
                   : (L == 1) ? (isR ? rW1 : W1) : (isR ? rW2 : W2);
    bf16_t* D = wts + L * 131072 + isR * 65536;  // [512 rows,128 cols]
#pragma unroll
    for (int rr = 0; rr < 4; rr++)
      tile[r + rr * 8][c] = S[(kt * 32 + r + rr * 8) * 512 + nt * 32 + c];
    __syncthreads();
#pragma unroll
    for (int rr = 0; rr < 4; rr++)
      D[(nt * 32 + r + rr * 8) * 128 + kt * 32 + c] =
          __float2bfloat16(tile[c][r + rr * 8]);
  } else if (b < 512) {  // DW transposes: [512,128] -> [128,512]; 2 mats x 64
    int i = b - 384;
    int mat = i >> 6;
    int t = i & 63;
    int kt = t & 15, nt = t >> 4;
    const float* S = mat ? DW1 : DW0;
    bf16_t* D = wts + 393216 + mat * 65536;  // [128 rows,512 cols]
#pragma unroll
    for (int rr = 0; rr < 4; rr++)
      tile[r + rr * 8][c] = S[(kt * 32 + r + rr * 8) * 128 + nt * 32 + c];
    __syncthreads();
#pragma unroll
    for (int rr = 0; rr < 4; rr++)
      D[(nt * 32 + r + rr * 8) * 512 + kt * 32 + c] =
          __float2bfloat16(tile[c][r + rr * 8]);
  } else if (b < 524) {  // ALR
    int idx = (b - 512) * 256 + tid;
    if (idx < 3072) {
      int L = idx >> 10;
      int k = (idx >> 3) & 127;
      int cc = idx & 7;
      int h = cc & 3;
      const float* W = (L == 0) ? W0 : (L == 1) ? W1 : W2;
      const float* a = (cc < 4) ? ((L == 0) ? al0 : (L == 1) ? al1 : al2)
                                : ((L == 0) ? ar0 : (L == 1) ? ar1 : ar2);
      float s = 0.f;
      for (int d = 0; d < 128; d++) s += W[k * 512 + h * 128 + d] * a[h * 128 + d];
      ALR[idx] = s;
    }
  } else if (b < 3024) {  // convert n_feat
    int i = ((b - 524) * 256 + tid) * 4;
    if (i < N * 128) {
      float4 v = *(const float4*)(n_feat + i);
      xbf[i + 0] = __float2bfloat16(v.x);
      xbf[i + 1] = __float2bfloat16(v.y);
      xbf[i + 2] = __float2bfloat16(v.z);
      xbf[i + 3] = __float2bfloat16(v.w);
    }
  } else {  // zero counts + d_out
    for (int i = tid; i < N; i += 256) counts[i] = 0;
    if (tid < 128) d_out_f[tid] = 0.f;
  }
}

// ---------------- 128x128-tile MFMA GEMM + fused el/er column (+opt count).
// blockIdx.x 0-3: feat cols -> featB[M,512]; 4-7: res cols -> resB[M,512]
// blockIdx.x == 8: el/er[rowtile]; blockIdx.x == 9 (COUNT only): degree count
template <bool COUNT>
__global__ __launch_bounds__(256) void gemm128el(
    const bf16_t* __restrict__ A, const bf16_t* __restrict__ Bt,
    const float* __restrict__ ALRl, bf16_t* __restrict__ featB,
    bf16_t* __restrict__ resB,
    float* __restrict__ el, float* __restrict__ er, int M, int K,
    const int* __restrict__ dst, int* __restrict__ counts, int E) {
  __shared__ bf16_t As[128 * 64];  // 16 KB, XOR-swizzled
  __shared__ bf16_t Bs[128 * 64];
  int tid = threadIdx.x;
  int rowBase = blockIdx.y * 128;

  if (COUNT && blockIdx.x == 9) {
    int stride = gridDim.y * 256;
    for (int i = blockIdx.y * 256 + tid; i < E; i += stride)
      atomicAdd(&counts[dst[i]], 1);
    return;
  }

  if (blockIdx.x == 8) {
    float* sALR = (float*)As;  // [128][8] fp32 = 4 KB
#pragma unroll
    for (int j = 0; j < 4; j++) sALR[tid * 4 + j] = ALRl[tid * 4 + j];
    __syncthreads();
    int row = rowBase + (tid >> 1);
    int half = tid & 1;
    if (row < M) {
      const bf16_t* xr = A + (size_t)row * K + half * 64;
      float s[8] = {};
#pragma unroll
      for (int g = 0; g < 8; g++) {
        bf16x8 v = *(const bf16x8*)(xr + g * 8);
#pragma unroll
        for (int e = 0; e < 8; e++) {
          float f = __uint_as_float(((unsigned int)(unsigned short)v[e]) << 16);
          const float* Ak = sALR + (half * 64 + g * 8 + e) * 8;
#pragma unroll
          for (int cc = 0; cc < 8; cc++) s[cc] += f * Ak[cc];
        }
      }
#pragma unroll
      for (int cc = 0; cc < 8; cc++) s[cc] += __shfl_xor(s[cc], 1);
      if (half == 0)
        *(float4*)(el + row * 4) = make_float4(s[0], s[1], s[2], s[3]);
      else
        *(float4*)(er + row * 4) = make_float4(s[4], s[5], s[6], s[7]);
    }
    return;
  }

  int lane = tid & 63, wave = tid >> 6;
  int q = lane >> 4, r16 = lane & 15;
  int wm = (wave >> 1) * 64, wn = (wave & 1) * 64;
  int colBase = blockIdx.x * 128;
  bf16_t* Cb = (colBase < 512) ? featB : resB;
  int colOff = (colBase < 512) ? colBase : colBase - 512;

  f32x4 acc[4][4] = {};

  for (int k0 = 0; k0 < K; k0 += 64) {
#pragma unroll
    for (int p = 0; p < 4; p++) {
      int slotb = (wave * 4 + p) * 64;
      int s = slotb + lane;
      int r = s >> 3;
      int c = (s & 7) ^ (r & 7);
      int gr = rowBase + r;
      if (gr > M - 1) gr = M - 1;
      gload_lds16(A + (size_t)gr * K + k0 + c * 8, (char*)As + (size_t)slotb * 16);
      gload_lds16(Bt + (size_t)(colBase + r) * K + k0 + c * 8,
                  (char*)Bs + (size_t)slotb * 16);
    }
    __syncthreads();
#pragma unroll
    for (int ks = 0; ks < 64; ks += 32) {
      int koff = ks >> 3;
      bf16x8 af[4], bfr[4];
#pragma unroll
      for (int i = 0; i < 4; i++) {
        int R = wm + i * 16 + r16;
        int slot = R * 8 + ((q + koff) ^ (R & 7));
        af[i] = *(const bf16x8*)((const char*)As + (size_t)slot * 16);
      }
#pragma unroll
      for (int j = 0; j < 4; j++) {
        int R = wn + j * 16 + r16;
        int slot = R * 8 + ((q + koff) ^ (R & 7));
        bfr[j] = *(const bf16x8*)((const char*)Bs + (size_t)slot * 16);
      }
#pragma unroll
      for (int i = 0; i < 4; i++)
#pragma unroll
        for (int j = 0; j < 4; j++)
          acc[i][j] = __builtin_amdgcn_mfma_f32_16x16x32_bf16(af[i], bfr[j], acc[i][j], 0, 0, 0);
    }
    __syncthreads();
  }

  int odd = lane & 1;
  int colb0 = r16 & ~1;
#pragma unroll
  for (int i = 0; i < 4; i++) {
#pragma unroll
    for (int r = 0; r < 4; r++) {
      int row = rowBase + wm + i * 16 + q * 4 + r;
#pragma unroll
      for (int jp = 0; jp < 2; jp++) {
        float a0 = acc[i][2 * jp][r];
        float a1 = acc[i][2 * jp + 1][r];
        float p0 = __shfl_xor(a0, 1);
        float p1 = __shfl_xor(a1, 1);
        float lo = odd ? p1 : a0;
        float hi = odd ? a1 : p0;
        int col = colOff + wn + (2 * jp + odd) * 16 + colb0;
        if (row < M)
          *(unsigned int*)(Cb + (size_t)row * 512 + col) = pack_bf16(lo, hi);
      }
    }
  }
}

// ---------------- 64x64-tile MFMA GEMM, BK=64, DMA-staged, bias+relu (dense)
__global__ __launch_bounds__(256) void mfma_gemm64(
    const bf16_t* __restrict__ A, const bf16_t* __restrict__ Bt,
    const float* __restrict__ bias, bf16_t* __restrict__ C,
    int M, int ldc, int K) {
  __shared__ bf16_t As[64 * 64];
  __shared__ bf16_t Bs[64 * 64];
  int tid = threadIdx.x;
  int lane = tid & 63, wave = tid >> 6;
  int q = lane >> 4, r16 = lane & 15;
  int wm = (wave >> 1) * 32, wn = (wave & 1) * 32;
  int rowBase = blockIdx.y * 64, colBase = blockIdx.x * 64;

  f32x4 acc[2][2] = {};

  for (int k0 = 0; k0 < K; k0 += 64) {
#pragma unroll
    for (int p = 0; p < 2; p++) {
      int slotb = (wave * 2 + p) * 64;
      int s = slotb + lane;
      int r = s >> 3;
      int c = (s & 7) ^ (r & 7);
      int gr = rowBase + r;
      if (gr > M - 1) gr = M - 1;
      gload_lds16(A + (size_t)gr * K + k0 + c * 8, (char*)As + (size_t)slotb * 16);
      gload_lds16(Bt + (size_t)(colBase + r) * K + k0 + c * 8,
                  (char*)Bs + (size_t)slotb * 16);
    }
    __syncthreads();
#pragma unroll
    for (int ks = 0; ks < 64; ks += 32) {
      int koff = ks >> 3;
      bf16x8 af[2], bfr[2];
#pragma unroll
      for (int i = 0; i < 2; i++) {
        int R = wm + i * 16 + r16;
        int slot = R * 8 + ((q + koff) ^ (R & 7));
        af[i] = *(const bf16x8*)((const char*)As + (size_t)slot * 16);
      }
#pragma unroll
      for (int j = 0; j < 2; j++) {
        int R = wn + j * 16 + r16;
        int slot = R * 8 + ((q + koff) ^ (R & 7));
        bfr[j] = *(const bf16x8*)((const char*)Bs + (size_t)slot * 16);
      }
#pragma unroll
      for (int i = 0; i < 2; i++)
#pragma unroll
        for (int j = 0; j < 2; j++)
          acc[i][j] = __builtin_amdgcn_mfma_f32_16x16x32_bf16(af[i], bfr[j], acc[i][j], 0, 0, 0);
    }
    __syncthreads();
  }

  int odd = lane & 1;
  int colb0 = r16 & ~1;
#pragma unroll
  for (int i = 0; i < 2; i++) {
#pragma unroll
    for (int r = 0; r < 4; r++) {
      int row = rowBase + wm + i * 16 + q * 4 + r;
      float a0 = acc[i][0][r];
      float a1 = acc[i][1][r];
      float p0 = __shfl_xor(a0, 1);
      float p1 = __shfl_xor(a1, 1);
      float lo = odd ? p1 : a0;
      float hi = odd ? a1 : p0;
      int col = colBase + wn + odd * 16 + colb0;
      if (row < M) {
        float o0 = fmaxf(lo + bias[col], 0.f);
        float o1 = fmaxf(hi + bias[col + 1], 0.f);
        *(unsigned int*)(C + (size_t)row * ldc + col) = pack_bf16(o0, o1);
      }
    }
  }
}

// ---------------- CSR scan
__global__ __launch_bounds__(1024) void scan_kernel(const int* __restrict__ counts,
                                                    int* __restrict__ row_ptr,
                                                    int* __restrict__ cursor, int N) {
  __shared__ int sums[1024];
  int t = threadIdx.x;
  int chunk = (N + 1023) / 1024;
  int begin = t * chunk;
  int end = begin + chunk;
  if (end > N) end = N;
  int s = 0;
  for (int i = begin; i < end; i++) s += counts[i];
  sums[t] = s;
  __syncthreads();
  for (int off = 1; off < 1024; off <<= 1) {
    int v = (t >= off) ? sums[t - off] : 0;
    __syncthreads();
    sums[t] += v;
    __syncthreads();
  }
  int run = (t == 0) ? 0 : sums[t - 1];
  for (int i = begin; i < end; i++) {
    row_ptr[i] = run;
    cursor[i] = run;
    run += counts[i];
  }
  if (t == 1023) row_ptr[N] = sums[1023];
}

// ---------------- scatter + layer-0 edge weights (head-major wcsrT[4][E])
__global__ __launch_bounds__(256) void scatter_w_kernel(
    const int* __restrict__ src, const int* __restrict__ dst,
    int* __restrict__ cursor, int* __restrict__ edge_src,
    int* __restrict__ edge_dst, const float* __restrict__ el,
    const float* __restrict__ er, float* __restrict__ wcsrT, int E) {
  int i = blockIdx.x * blockDim.x + threadIdx.x;
  if (i < E) {
    int s = src[i];
    int d = dst[i];
    int pos = atomicAdd(&cursor[d], 1);
    edge_src[pos] = s;
    edge_dst[pos] = d;
    float4 elv = *(const float4*)(el + s * 4);
    float4 erv = *(const float4*)(er + d * 4);
    wcsrT[0 * E + pos] = leaky_exp(elv.x + erv.x);
    wcsrT[1 * E + pos] = leaky_exp(elv.y + erv.y);
    wcsrT[2 * E + pos] = leaky_exp(elv.z + erv.z);
    wcsrT[3 * E + pos] = leaky_exp(elv.w + erv.w);
  }
}

// ---------------- edge weights for layers 1/2 (CSR order, head-major)
__global__ __launch_bounds__(256) void w_pass_kernel(
    const int* __restrict__ edge_src, const int* __restrict__ edge_dst,
    const float* __restrict__ el, const float* __restrict__ er,
    float* __restrict__ wcsrT, int E) {
  int p = blockIdx.x * blockDim.x + threadIdx.x;
  if (p < E) {
    int s = edge_src[p];
    int d = edge_dst[p];
    float4 elv = *(const float4*)(el + s * 4);
    float4 erv = *(const float4*)(er + d * 4);
    wcsrT[0 * E + p] = leaky_exp(elv.x + erv.x);
    wcsrT[1 * E + p] = leaky_exp(elv.y + erv.y);
    wcsrT[2 * E + p] = leaky_exp(elv.z + erv.z);
    wcsrT[3 * E + p] = leaky_exp(elv.w + erv.w);
  }
}

// ---------------- XCD-sliced GAT aggregation.
// block = (slice s = blockIdx&7, chunk of 8 nodes). 256 threads = 32 groups
// of 8 lanes; group = (subgroup 0..3, node slot 0..7). Group walks node's
// edges with stride 4, gathering only dims [s*64, s*64+64) (128 B / edge).
// Per-XCD feat footprint = 2.56 MB -> L2-resident under %8 XCD round-robin.
__global__ __launch_bounds__(256) void gat_agg_sliced(
    const bf16_t* __restrict__ featB,  // [N,512]
    const bf16_t* __restrict__ resB,   // [N,512]
    const float* __restrict__ wcsrT,   // [4][E] head-major, CSR order
    const float* __restrict__ bias, const int* __restrict__ row_ptr,
    const int* __restrict__ edge_src, bf16_t* __restrict__ out, int N, int E) {
  __shared__ float accS[4][8][64];  // [sub][nslot][dim] 8 KB
  __shared__ float ssumS[4][8];
  int bx = blockIdx.x;
  int s = bx & 7;                    // slice -> XCD (round-robin heuristic)
  int chunk = bx >> 3;
  int tid = threadIdx.x;
  int gid = tid >> 3, t8 = tid & 7;
  int nslot = gid & 7, sub = gid >> 3;
  int n = chunk * 8 + nslot;
  int head = s >> 1;

  float acc[8] = {};
  float ssum = 0.f;
  if (n < N) {
    int start = row_ptr[n];
    int deg = row_ptr[n + 1] - start;
    const float* wbase = wcsrT + (size_t)head * E;
    const bf16_t* fbase = featB + s * 64 + t8 * 8;
    for (int i = sub; i < deg; i += 4) {
      int p = start + i;
      int e = edge_src[p];            // broadcast within group
      float wv = wbase[p];            // broadcast within group
      ssum += wv;
      uint4 f = *(const uint4*)(fbase + (size_t)e * 512);  // 16B, this slice
      unsigned int u[4] = {f.x, f.y, f.z, f.w};
#pragma unroll
      for (int j = 0; j < 4; j++) {
        acc[2 * j] += wv * __uint_as_float(u[j] << 16);
        acc[2 * j + 1] += wv * __uint_as_float(u[j] & 0xffff0000u);
      }
    }
  }
  *(float4*)&accS[sub][nslot][t8 * 8] = make_float4(acc[0], acc[1], acc[2], acc[3]);
  *(float4*)&accS[sub][nslot][t8 * 8 + 4] = make_float4(acc[4], acc[5], acc[6], acc[7]);
  if (t8 == 0) ssumS[sub][nslot] = ssum;
  __syncthreads();

  // finalize: thread covers (node slot, 2 dims): idx = tid*2 over 8x64
  int idx = tid * 2;
  int ns2 = idx >> 6;
  int d2 = idx & 63;
  int n2 = chunk * 8 + ns2;
  if (n2 >= N) return;
  float a0 = accS[0][ns2][d2] + accS[1][ns2][d2] + accS[2][ns2][d2] + accS[3][ns2][d2];
  float a1 = accS[0][ns2][d2 + 1] + accS[1][ns2][d2 + 1] + accS[2][ns2][d2 + 1] +
             accS[3][ns2][d2 + 1];
  float ssum4 = ssumS[0][ns2] + ssumS[1][ns2] + ssumS[2][ns2] + ssumS[3][ns2];
  float inv = (ssum4 > 0.f) ? 1.f / ssum4 : 0.f;  // weights>0, so ssum>0 iff deg>0
  int dg = s * 64 + d2;
  unsigned int ru = *(const unsigned int*)(resB + (size_t)n2 * 512 + dg);
  float2 bv = *(const float2*)(bias + dg);
  float o0 = fmaxf(a0 * inv + __uint_as_float(ru << 16) + bv.x, 0.f);
  float o1 = fmaxf(a1 * inv + __uint_as_float(ru & 0xffff0000u) + bv.y, 0.f);
  *(unsigned int*)(out + (size_t)n2 * 512 + dg) = pack_bf16(o0, o1);
}

// ---------------- graph pool: head-mean -> relu -> max over nodes (d_out pre-zeroed)
__global__ __launch_bounds__(128) void pool_kernel(const bf16_t* __restrict__ g,
                                                   float* __restrict__ out, int N) {
  int d = threadIdx.x;  // 0..127
  float mx = 0.f;
  for (int n = blockIdx.x; n < N; n += gridDim.x) {
    const bf16_t* p = g + (size_t)n * 512 + d;
    float v = 0.25f * (__bfloat162float(p[0]) + __bfloat162float(p[128]) +
                       __bfloat162float(p[256]) + __bfloat162float(p[384]));
    mx = fmaxf(mx, v);
  }
  atomicMax((int*)out + d, __float_as_int(mx));  // values are >= 0
}

// ---------------------------------------------------------------------------
extern "C" void kernel_launch(void* const* d_in, const int* in_sizes, int n_in,
                              void* d_out, int out_size, void* d_ws, size_t ws_size,
                              hipStream_t stream) {
  const float* n_feat = (const float*)d_in[0];
  const int* src = (const int*)d_in[1];
  const int* dst = (const int*)d_in[2];
  const float* W0 = (const float*)d_in[3];
  const float* al0 = (const float*)d_in[4];
  const float* ar0 = (const float*)d_in[5];
  const float* b0 = (const float*)d_in[6];
  const float* rW0 = (const float*)d_in[7];
  const float* DW0 = (const float*)d_in[8];
  const float* Db0 = (const float*)d_in[9];
  const float* W1 = (const float*)d_in[10];
  const float* al1 = (const float*)d_in[11];
  const float* ar1 = (const float*)d_in[12];
  const float* b1 = (const float*)d_in[13];
  const float* rW1 = (const float*)d_in[14];
  const float* DW1 = (const float*)d_in[15];
  const float* Db1 = (const float*)d_in[16];
  const float* W2 = (const float*)d_in[17];
  const float* al2 = (const float*)d_in[18];
  const float* ar2 = (const float*)d_in[19];
  const float* b2 = (const float*)d_in[20];
  const float* rW2 = (const float*)d_in[21];

  const int N = in_sizes[0] / 128;
  const int E = in_sizes[1];

  // ---- workspace carve-up (16B-aligned throughout)
  bf16_t* xbf = (bf16_t*)d_ws;                        // [N,128]
  bf16_t* featB = xbf + (size_t)N * 128;              // [N,512]
  bf16_t* resB = featB + (size_t)N * 512;             // [N,512]
  bf16_t* outC = resB + (size_t)N * 512;              // [N,512]
  bf16_t* denseD = outC + (size_t)N * 512;            // [N,128]
  bf16_t* wts = denseD + (size_t)N * 128;             // 524288
  float* ALR = (float*)(wts + 524288);                // [3][128][8]
  float* el = ALR + 3072;                             // [N,4]
  float* er = el + (size_t)N * 4;                     // [N,4]
  float* wcsrT = er + (size_t)N * 4;                  // [4][E]
  int* counts = (int*)(wcsrT + (size_t)E * 4);        // [N]
  int* row_ptr = counts + N;                          // [N+1]
  int* cursor = row_ptr + (N + 1);                    // [N]
  int* edge_src = cursor + N;                         // [E]
  int* edge_dst = edge_src + E;                       // [E]

  bf16_t* FW0 = wts;                // [1024,128]
  bf16_t* FW1 = wts + 131072;
  bf16_t* FW2 = wts + 262144;
  bf16_t* DWt0 = wts + 393216;      // [128,512]
  bf16_t* DWt1 = wts + 458752;

  // ---- 1: weights transpose + ALR + convert + zero counts/d_out
  mega_prep<<<3025, 256, 0, stream>>>(
      W0, rW0, W1, rW1, W2, rW2, DW0, DW1,
      al0, ar0, al1, ar1, al2, ar2,
      n_feat, wts, ALR, xbf, counts, (float*)d_out, N);

  int nRow = (N + 127) / 128;       // 157
  dim3 gF0(10, nRow);               // 8 col-tiles + el/er + count
  dim3 gF(9, nRow);                 // 8 col-tiles + el/er
  dim3 gD(2, (N + 63) / 64);        // dense: 128 cols, 64-tile
  int gE = (E + 255) / 256;
  int gAgg = ((N + 7) / 8) * 8;     // (slice, chunk) blocks

  // ---- 2: layer-0 GEMM + el/er + CSR count
  gemm128el<true><<<gF0, 256, 0, stream>>>(xbf, FW0, ALR, featB, resB, el, er,
                                           N, 128, dst, counts, E);
  // ---- 3,4: CSR scan; scatter fused with layer-0 edge weights
  scan_kernel<<<1, 1024, 0, stream>>>(counts, row_ptr, cursor, N);
  scatter_w_kernel<<<gE, 256, 0, stream>>>(src, dst, cursor, edge_src, edge_dst,
                                           el, er, wcsrT, E);

  // ---- 5-6: layer 0 agg + dense
  gat_agg_sliced<<<gAgg, 256, 0, stream>>>(featB, resB, wcsrT, b0, row_ptr,
                                           edge_src, outC, N, E);
  mfma_gemm64<<<gD, 256, 0, stream>>>(outC, DWt0, Db0, denseD, N, 128, 512);
  // ---- 7-9: layer 1 GEMM + weights + agg
  gemm128el<false><<<gF, 256, 0, stream>>>(denseD, FW1, ALR + 1024, featB, resB,
                                           el, er, N, 128, nullptr, nullptr, 0);
  w_pass_kernel<<<gE, 256, 0, stream>>>(edge_src, edge_dst, el, er, wcsrT, E);
  gat_agg_sliced<<<gAgg, 256, 0, stream>>>(featB, resB, wcsrT, b1, row_ptr,
                                           edge_src, outC, N, E);
  // ---- 10-12: dense; layer 2 GEMM + weights
  mfma_gemm64<<<gD, 256, 0, stream>>>(outC, DWt1, Db1, denseD, N, 128, 512);
  gemm128el<false><<<gF, 256, 0, stream>>>(denseD, FW2, ALR + 2048, featB, resB,
                                           el, er, N, 128, nullptr, nullptr, 0);
  w_pass_kernel<<<gE, 256, 0, stream>>>(edge_src, edge_dst, el, er, wcsrT, E);
  // ---- 13: layer 2 agg
  gat_agg_sliced<<<gAgg, 256, 0, stream>>>(featB, resB, wcsrT, b2, row_ptr,
                                           edge_src, outC, N, E);
  // ---- 14: pool (d_out pre-zeroed in mega_prep)
  pool_kernel<<<256, 128, 0, stream>>>(outC, (float*)d_out, N);
}